// Round 1
// baseline (112.539 us; speedup 1.0000x reference)
//
#include <hip/hip_runtime.h>
#include <hip/hip_bf16.h>

typedef __bf16 bf16x4 __attribute__((ext_vector_type(4)));
typedef __bf16 bf16x8 __attribute__((ext_vector_type(8)));
typedef float  f32x4  __attribute__((ext_vector_type(4)));

#define H_  8
#define D_  32
#define L_  4096
#define S_  4096
#define BM  64
#define BN  64
#define NSPLIT 4

static __device__ __forceinline__ f32x4 mfma_k16(bf16x4 a, bf16x4 b, f32x4 c) {
#if __has_builtin(__builtin_amdgcn_mfma_f32_16x16x16_bf16)
    return __builtin_amdgcn_mfma_f32_16x16x16_bf16(a, b, c, 0, 0, 0);
#elif __has_builtin(__builtin_amdgcn_mfma_f32_16x16x16bf16_1k)
    typedef short s16x4 __attribute__((ext_vector_type(4)));
    union U { bf16x4 h; s16x4 s; };
    U ua, ub; ua.h = a; ub.h = b;
    return __builtin_amdgcn_mfma_f32_16x16x16bf16_1k(ua.s, ub.s, c, 0, 0, 0);
#else
    asm("v_mfma_f32_16x16x16_bf16 %0, %1, %2, %0" : "+v"(c) : "v"(a), "v"(b));
    return c;
#endif
}

// Two-kernel split-S (NO fences/atomics — r20/r21 lesson: device-scope fences
// in the tail L2-invalidate-storm co-resident blocks: 55us -> 325us).
// Main loop: S^T formulation (P in registers), no-max softmax, scale folded
// into Q, rotation-swizzled Vt, double-buffered LDS with register prefetch.
// __launch_bounds__(256,6): VGPR cap ~85 so the 16 prefetch VGPRs do NOT
// spill (r20 lesson: (256,8) caps at 64 -> scratch spills in the K-loop).
template<bool DIRECT>
__global__ __launch_bounds__(256, 6)
void fattn_main(const float* __restrict__ q, const float* __restrict__ kk,
                const float* __restrict__ v, float* __restrict__ num,
                float* __restrict__ den, float* __restrict__ out, int schunk)
{
    const int qt = blockIdx.x, h = blockIdx.y, sp = blockIdx.z;
    const int tid = threadIdx.x, wave = tid >> 6, lane = tid & 63;
    const int col = lane & 15, quad = lane >> 4;

    __shared__ __align__(16) __bf16 Ks[2][BN][40];
    __shared__ __align__(16) __bf16 Vt[2][D_][72];

    const float cs = 0.17677669529663687f * 1.4426950408889634f; // log2e/sqrt(32)

    const int qn = qt * BM + wave * 16 + col;
    bf16x8 qb;
    {
        const float* qp = q + ((size_t)qn * H_ + h) * D_ + quad * 8;
        float4 q0 = *(const float4*)qp;
        float4 q1 = *(const float4*)(qp + 4);
        qb[0]=(__bf16)(q0.x*cs); qb[1]=(__bf16)(q0.y*cs);
        qb[2]=(__bf16)(q0.z*cs); qb[3]=(__bf16)(q0.w*cs);
        qb[4]=(__bf16)(q1.x*cs); qb[5]=(__bf16)(q1.y*cs);
        qb[6]=(__bf16)(q1.z*cs); qb[7]=(__bf16)(q1.w*cs);
    }

    f32x4 o0 = {0,0,0,0}, o1 = {0,0,0,0}, accl = {0,0,0,0};
    const f32x4 zc = {0,0,0,0};
    const bf16x4 ones = {(__bf16)1.f, (__bf16)1.f, (__bf16)1.f, (__bf16)1.f};

    const int srow = tid >> 2;                 // staged KV row
    const int g    = tid & 3;                  // staged d-octave
    const int dseg = g * 8;
    const int vcol = (srow + 16 * g) & 63;     // rotated column (wrap!)
    const int rot0 = (col >> 3) << 4;          // read rotation for d=col

    const int sbeg = sp * schunk;
    const int T = schunk / BN;

    float4 kf0, kf1, vf0, vf1;
    {
        const size_t goff = ((size_t)(sbeg + srow) * H_ + h) * D_ + dseg;
        kf0 = *(const float4*)(kk + goff);
        kf1 = *(const float4*)(kk + goff + 4);
        vf0 = *(const float4*)(v + goff);
        vf1 = *(const float4*)(v + goff + 4);
    }
    float4 kn0 = kf0, kn1 = kf1, vn0 = vf0, vn1 = vf1;

    for (int t = 0; t < T; ++t) {
        const int b = t & 1;
        {   // stage current regs -> LDS buffer b (b last read at t-2; barrier(t-1) protects)
            bf16x8 kb;
            kb[0]=(__bf16)kf0.x; kb[1]=(__bf16)kf0.y; kb[2]=(__bf16)kf0.z; kb[3]=(__bf16)kf0.w;
            kb[4]=(__bf16)kf1.x; kb[5]=(__bf16)kf1.y; kb[6]=(__bf16)kf1.z; kb[7]=(__bf16)kf1.w;
            *(bf16x8*)(&Ks[b][srow][dseg]) = kb;
            float vv[8] = {vf0.x, vf0.y, vf0.z, vf0.w, vf1.x, vf1.y, vf1.z, vf1.w};
#pragma unroll
            for (int j = 0; j < 8; ++j)
                Vt[b][dseg + j][vcol] = (__bf16)vv[j];
        }
        if (t + 1 < T) {   // prefetch next tile; lands during this tile's compute
            const size_t goff = ((size_t)(sbeg + (t+1)*BN + srow) * H_ + h) * D_ + dseg;
            kn0 = *(const float4*)(kk + goff);
            kn1 = *(const float4*)(kk + goff + 4);
            vn0 = *(const float4*)(v + goff);
            vn1 = *(const float4*)(v + goff + 4);
        }
        __syncthreads();   // single barrier per tile

#pragma unroll
        for (int sb = 0; sb < 4; ++sb) {
            bf16x8 ka = *(const bf16x8*)(&Ks[b][sb * 16 + col][quad * 8]);
            f32x4 st = __builtin_amdgcn_mfma_f32_16x16x32_bf16(ka, qb, zc, 0, 0, 0);
            bf16x4 pb;
#pragma unroll
            for (int r = 0; r < 4; ++r)
                pb[r] = (__bf16)__builtin_amdgcn_exp2f(st[r]);
            const int sc  = sb * 16 + quad * 4;
            bf16x4 va0 = *(const bf16x4*)(&Vt[b][col     ][(sc + rot0)      & 63]);
            bf16x4 va1 = *(const bf16x4*)(&Vt[b][col + 16][(sc + rot0 + 32) & 63]);
            o0   = mfma_k16(va0,  pb, o0);
            o1   = mfma_k16(va1,  pb, o1);
            accl = mfma_k16(ones, pb, accl);
        }
        kf0 = kn0; kf1 = kn1; vf0 = vn0; vf1 = vn1;
    }

    if (DIRECT) {
        const float inv = 1.f / accl[0];
        float* op = out + ((size_t)qn * H_ + h) * D_;
        f32x4 r0 = {o0[0]*inv, o0[1]*inv, o0[2]*inv, o0[3]*inv};
        f32x4 r1 = {o1[0]*inv, o1[1]*inv, o1[2]*inv, o1[3]*inv};
        *(f32x4*)(op + quad * 4)      = r0;
        *(f32x4*)(op + 16 + quad * 4) = r1;
    } else {
        float* pr = num + (((size_t)(sp * H_ + h) * L_ + qn) << 5);
        *(f32x4*)(pr + quad * 4)      = o0;
        *(f32x4*)(pr + 16 + quad * 4) = o1;
        if (quad == 0) den[(size_t)(sp * H_ + h) * L_ + qn] = accl[0];
    }
}

__global__ __launch_bounds__(256)
void fattn_combine(const float* __restrict__ num, const float* __restrict__ den,
                   float* __restrict__ out)
{
    const int i  = blockIdx.x * 256 + threadIdx.x;  // one float4 of output
    const int d4 = (i & 7) * 4;
    const int h  = (i >> 3) & 7;
    const int l  = i >> 6;
    f32x4 acc = {0,0,0,0};
    float dn = 0.f;
    for (int sp = 0; sp < NSPLIT; ++sp) {
        const float* pr = num + (((size_t)(sp * H_ + h) * L_ + l) << 5) + d4;
        f32x4 t = *(const f32x4*)pr;
        acc[0] += t[0]; acc[1] += t[1]; acc[2] += t[2]; acc[3] += t[3];
        dn += den[(size_t)(sp * H_ + h) * L_ + l];
    }
    const float inv = 1.f / dn;
    f32x4 r = {acc[0]*inv, acc[1]*inv, acc[2]*inv, acc[3]*inv};
    *(f32x4*)(out + ((size_t)l * H_ + h) * D_ + d4) = r;
}

extern "C" void kernel_launch(void* const* d_in, const int* in_sizes, int n_in,
                              void* d_out, int out_size, void* d_ws, size_t ws_size,
                              hipStream_t stream) {
    const float* q = (const float*)d_in[0];
    const float* k = (const float*)d_in[1];
    const float* v = (const float*)d_in[2];
    float* out = (float*)d_out;
    const size_t nnum = (size_t)NSPLIT * H_ * L_ * 32;
    const size_t nden = (size_t)NSPLIT * H_ * L_;
    if (ws_size >= (nnum + nden) * sizeof(float)) {
        float* num = (float*)d_ws;
        float* den = num + nnum;
        fattn_main<false><<<dim3(L_ / BM, H_, NSPLIT), 256, 0, stream>>>(
            q, k, v, num, den, out, S_ / NSPLIT);
        fattn_combine<<<dim3((L_ * H_ * D_ / 4) / 256), 256, 0, stream>>>(num, den, out);
    } else {
        fattn_main<true><<<dim3(L_ / BM, H_, 1), 256, 0, stream>>>(
            q, k, v, nullptr, nullptr, out, S_);
    }
}

// Round 2
// 112.243 us; speedup vs baseline: 1.0026x; 1.0026x over previous
//
#include <hip/hip_runtime.h>
#include <hip/hip_bf16.h>

typedef __bf16 bf16x4 __attribute__((ext_vector_type(4)));
typedef __bf16 bf16x8 __attribute__((ext_vector_type(8)));
typedef float  f32x4  __attribute__((ext_vector_type(4)));

#define H_  8
#define D_  32
#define L_  4096
#define S_  4096
#define BM  64
#define BN  64
#define NSPLIT 4

static __device__ __forceinline__ f32x4 mfma_k16(bf16x4 a, bf16x4 b, f32x4 c) {
#if __has_builtin(__builtin_amdgcn_mfma_f32_16x16x16_bf16)
    return __builtin_amdgcn_mfma_f32_16x16x16_bf16(a, b, c, 0, 0, 0);
#elif __has_builtin(__builtin_amdgcn_mfma_f32_16x16x16bf16_1k)
    typedef short s16x4 __attribute__((ext_vector_type(4)));
    union U { bf16x4 h; s16x4 s; };
    U ua, ub; ua.h = a; ub.h = b;
    return __builtin_amdgcn_mfma_f32_16x16x16bf16_1k(ua.s, ub.s, c, 0, 0, 0);
#else
    asm("v_mfma_f32_16x16x16_bf16 %0, %1, %2, %0" : "+v"(c) : "v"(a), "v"(b));
    return c;
#endif
}

// ---------- pre-pass: K f32 [s][h][d] -> bf16 Kb [h][s][d] ----------
__global__ __launch_bounds__(256)
void prep_k(const float* __restrict__ kk, __bf16* __restrict__ kb)
{
    const int oi = blockIdx.x * 256 + threadIdx.x;   // one bf16x8 group
    const int h    = oi >> 14;                       // S_*D_/8 = 16384 groups/head
    const int s    = (oi >> 2) & (S_ - 1);
    const int dseg = (oi & 3) * 8;
    const float* ip = kk + (((size_t)s * H_ + h) * D_ + dseg);
    float4 a = *(const float4*)ip, b = *(const float4*)(ip + 4);
    bf16x8 o;
    o[0]=(__bf16)a.x; o[1]=(__bf16)a.y; o[2]=(__bf16)a.z; o[3]=(__bf16)a.w;
    o[4]=(__bf16)b.x; o[5]=(__bf16)b.y; o[6]=(__bf16)b.z; o[7]=(__bf16)b.w;
    *(bf16x8*)(kb + ((size_t)h * S_ + s) * D_ + dseg) = o;
}

// ---------- pre-pass: V f32 [s][h][d] -> bf16 Vtg [h][d][s] (transpose) ----------
__global__ __launch_bounds__(256)
void prep_v(const float* __restrict__ v, __bf16* __restrict__ vt)
{
    const int h  = blockIdx.y;
    const int s0 = blockIdx.x * 64;
    __shared__ __bf16 T[D_][72];
    const int sr = threadIdx.x >> 2, dseg = (threadIdx.x & 3) * 8;
    const float* ip = v + (((size_t)(s0 + sr) * H_ + h) * D_ + dseg);
    float4 a = *(const float4*)ip, b = *(const float4*)(ip + 4);
    float vv[8] = {a.x, a.y, a.z, a.w, b.x, b.y, b.z, b.w};
#pragma unroll
    for (int j = 0; j < 8; ++j) T[dseg + j][sr] = (__bf16)vv[j];
    __syncthreads();
    const int d = threadIdx.x >> 3, so = (threadIdx.x & 7) * 8;
    bf16x8 o = *(const bf16x8*)(&T[d][so]);
    *(bf16x8*)(vt + ((size_t)h * D_ + d) * S_ + s0 + so) = o;
}

// ---------- main kernel v2: stages pre-converted bf16 K / pre-transposed bf16 V ----------
// Same S^T formulation / no-max softmax / rotation-swizzled Vt / register-prefetch
// double-buffer as the proven v1, but staging is now 2x bf16x8 load + 2x ds_write_b128
// per thread per tile (was 4x float4 load + 16 cvt + 1 b128 + 8 scalar b16 scatter).
__global__ __launch_bounds__(256, 6)
void fattn_v2(const __bf16* __restrict__ kb, const __bf16* __restrict__ vtg,
              const float* __restrict__ q, float* __restrict__ num,
              float* __restrict__ den, int schunk)
{
    const int qt = blockIdx.x, h = blockIdx.y, sp = blockIdx.z;
    const int tid = threadIdx.x, wave = tid >> 6, lane = tid & 63;
    const int col = lane & 15, quad = lane >> 4;

    __shared__ __align__(16) __bf16 Ks[2][BN][40];
    __shared__ __align__(16) __bf16 Vt[2][D_][72];

    const float cs = 0.17677669529663687f * 1.4426950408889634f; // log2e/sqrt(32)

    const int qn = qt * BM + wave * 16 + col;
    bf16x8 qb;
    {
        const float* qp = q + ((size_t)qn * H_ + h) * D_ + quad * 8;
        float4 q0 = *(const float4*)qp;
        float4 q1 = *(const float4*)(qp + 4);
        qb[0]=(__bf16)(q0.x*cs); qb[1]=(__bf16)(q0.y*cs);
        qb[2]=(__bf16)(q0.z*cs); qb[3]=(__bf16)(q0.w*cs);
        qb[4]=(__bf16)(q1.x*cs); qb[5]=(__bf16)(q1.y*cs);
        qb[6]=(__bf16)(q1.z*cs); qb[7]=(__bf16)(q1.w*cs);
    }

    f32x4 o0 = {0,0,0,0}, o1 = {0,0,0,0}, accl = {0,0,0,0};
    const f32x4 zc = {0,0,0,0};
    const bf16x4 ones = {(__bf16)1.f, (__bf16)1.f, (__bf16)1.f, (__bf16)1.f};

    // staging indices
    const int srow = tid >> 2, kseg = (tid & 3) * 8;       // K: row, d-octave
    const int vd   = tid >> 3, vso  = (tid & 7) * 8;       // V: d-row, s-octave
    const int vcolw = (vso + 16 * (vd >> 3)) & 63;         // rotated write col base
    const int rot0  = (col >> 3) << 4;                     // read rotation for d=col

    const int sbeg = sp * schunk;
    const int T = schunk / BN;

    const __bf16* kptr = kb  + ((size_t)h * S_ + sbeg + srow) * D_ + kseg;
    const __bf16* vptr = vtg + ((size_t)h * D_ + vd) * S_ + sbeg + vso;

    bf16x8 kf = *(const bf16x8*)kptr;
    bf16x8 vf = *(const bf16x8*)vptr;
    bf16x8 kn = kf, vn = vf;

    for (int t = 0; t < T; ++t) {
        const int b = t & 1;
        // stage current regs -> LDS buffer b (b last read at t-2; barrier(t-1) protects)
        *(bf16x8*)(&Ks[b][srow][kseg]) = kf;
        *(bf16x8*)(&Vt[b][vd][vcolw])  = vf;
        if (t + 1 < T) {   // prefetch next tile; lands during this tile's compute
            kn = *(const bf16x8*)(kptr + (size_t)(t + 1) * BN * D_);
            vn = *(const bf16x8*)(vptr + (t + 1) * BN);
        }
        __syncthreads();   // single barrier per tile

#pragma unroll
        for (int sb = 0; sb < 4; ++sb) {
            bf16x8 ka = *(const bf16x8*)(&Ks[b][sb * 16 + col][quad * 8]);
            f32x4 st = __builtin_amdgcn_mfma_f32_16x16x32_bf16(ka, qb, zc, 0, 0, 0);
            bf16x4 pb;
#pragma unroll
            for (int r = 0; r < 4; ++r)
                pb[r] = (__bf16)__builtin_amdgcn_exp2f(st[r]);
            const int sc  = sb * 16 + quad * 4;
            bf16x4 va0 = *(const bf16x4*)(&Vt[b][col     ][(sc + rot0)      & 63]);
            bf16x4 va1 = *(const bf16x4*)(&Vt[b][col + 16][(sc + rot0 + 32) & 63]);
            o0   = mfma_k16(va0,  pb, o0);
            o1   = mfma_k16(va1,  pb, o1);
            accl = mfma_k16(ones, pb, accl);
        }
        kf = kn; vf = vn;
    }

    float* pr = num + (((size_t)(sp * H_ + h) * L_ + qn) << 5);
    *(f32x4*)(pr + quad * 4)      = o0;
    *(f32x4*)(pr + 16 + quad * 4) = o1;
    if (quad == 0) den[(size_t)(sp * H_ + h) * L_ + qn] = accl[0];
}

// ---------- v1 kernel kept verbatim as fallback (small-workspace paths) ----------
template<bool DIRECT>
__global__ __launch_bounds__(256, 6)
void fattn_main(const float* __restrict__ q, const float* __restrict__ kk,
                const float* __restrict__ v, float* __restrict__ num,
                float* __restrict__ den, float* __restrict__ out, int schunk)
{
    const int qt = blockIdx.x, h = blockIdx.y, sp = blockIdx.z;
    const int tid = threadIdx.x, wave = tid >> 6, lane = tid & 63;
    const int col = lane & 15, quad = lane >> 4;

    __shared__ __align__(16) __bf16 Ks[2][BN][40];
    __shared__ __align__(16) __bf16 Vt[2][D_][72];

    const float cs = 0.17677669529663687f * 1.4426950408889634f;

    const int qn = qt * BM + wave * 16 + col;
    bf16x8 qb;
    {
        const float* qp = q + ((size_t)qn * H_ + h) * D_ + quad * 8;
        float4 q0 = *(const float4*)qp;
        float4 q1 = *(const float4*)(qp + 4);
        qb[0]=(__bf16)(q0.x*cs); qb[1]=(__bf16)(q0.y*cs);
        qb[2]=(__bf16)(q0.z*cs); qb[3]=(__bf16)(q0.w*cs);
        qb[4]=(__bf16)(q1.x*cs); qb[5]=(__bf16)(q1.y*cs);
        qb[6]=(__bf16)(q1.z*cs); qb[7]=(__bf16)(q1.w*cs);
    }

    f32x4 o0 = {0,0,0,0}, o1 = {0,0,0,0}, accl = {0,0,0,0};
    const f32x4 zc = {0,0,0,0};
    const bf16x4 ones = {(__bf16)1.f, (__bf16)1.f, (__bf16)1.f, (__bf16)1.f};

    const int srow = tid >> 2;
    const int g    = tid & 3;
    const int dseg = g * 8;
    const int vcol = (srow + 16 * g) & 63;
    const int rot0 = (col >> 3) << 4;

    const int sbeg = sp * schunk;
    const int T = schunk / BN;

    float4 kf0, kf1, vf0, vf1;
    {
        const size_t goff = ((size_t)(sbeg + srow) * H_ + h) * D_ + dseg;
        kf0 = *(const float4*)(kk + goff);
        kf1 = *(const float4*)(kk + goff + 4);
        vf0 = *(const float4*)(v + goff);
        vf1 = *(const float4*)(v + goff + 4);
    }
    float4 kn0 = kf0, kn1 = kf1, vn0 = vf0, vn1 = vf1;

    for (int t = 0; t < T; ++t) {
        const int b = t & 1;
        {
            bf16x8 kb;
            kb[0]=(__bf16)kf0.x; kb[1]=(__bf16)kf0.y; kb[2]=(__bf16)kf0.z; kb[3]=(__bf16)kf0.w;
            kb[4]=(__bf16)kf1.x; kb[5]=(__bf16)kf1.y; kb[6]=(__bf16)kf1.z; kb[7]=(__bf16)kf1.w;
            *(bf16x8*)(&Ks[b][srow][dseg]) = kb;
            float vv[8] = {vf0.x, vf0.y, vf0.z, vf0.w, vf1.x, vf1.y, vf1.z, vf1.w};
#pragma unroll
            for (int j = 0; j < 8; ++j)
                Vt[b][dseg + j][vcol] = (__bf16)vv[j];
        }
        if (t + 1 < T) {
            const size_t goff = ((size_t)(sbeg + (t+1)*BN + srow) * H_ + h) * D_ + dseg;
            kn0 = *(const float4*)(kk + goff);
            kn1 = *(const float4*)(kk + goff + 4);
            vn0 = *(const float4*)(v + goff);
            vn1 = *(const float4*)(v + goff + 4);
        }
        __syncthreads();

#pragma unroll
        for (int sb = 0; sb < 4; ++sb) {
            bf16x8 ka = *(const bf16x8*)(&Ks[b][sb * 16 + col][quad * 8]);
            f32x4 st = __builtin_amdgcn_mfma_f32_16x16x32_bf16(ka, qb, zc, 0, 0, 0);
            bf16x4 pb;
#pragma unroll
            for (int r = 0; r < 4; ++r)
                pb[r] = (__bf16)__builtin_amdgcn_exp2f(st[r]);
            const int sc  = sb * 16 + quad * 4;
            bf16x4 va0 = *(const bf16x4*)(&Vt[b][col     ][(sc + rot0)      & 63]);
            bf16x4 va1 = *(const bf16x4*)(&Vt[b][col + 16][(sc + rot0 + 32) & 63]);
            o0   = mfma_k16(va0,  pb, o0);
            o1   = mfma_k16(va1,  pb, o1);
            accl = mfma_k16(ones, pb, accl);
        }
        kf0 = kn0; kf1 = kn1; vf0 = vn0; vf1 = vn1;
    }

    if (DIRECT) {
        const float inv = 1.f / accl[0];
        float* op = out + ((size_t)qn * H_ + h) * D_;
        f32x4 r0 = {o0[0]*inv, o0[1]*inv, o0[2]*inv, o0[3]*inv};
        f32x4 r1 = {o1[0]*inv, o1[1]*inv, o1[2]*inv, o1[3]*inv};
        *(f32x4*)(op + quad * 4)      = r0;
        *(f32x4*)(op + 16 + quad * 4) = r1;
    } else {
        float* pr = num + (((size_t)(sp * H_ + h) * L_ + qn) << 5);
        *(f32x4*)(pr + quad * 4)      = o0;
        *(f32x4*)(pr + 16 + quad * 4) = o1;
        if (quad == 0) den[(size_t)(sp * H_ + h) * L_ + qn] = accl[0];
    }
}

__global__ __launch_bounds__(256)
void fattn_combine(const float* __restrict__ num, const float* __restrict__ den,
                   float* __restrict__ out)
{
    const int i  = blockIdx.x * 256 + threadIdx.x;
    const int d4 = (i & 7) * 4;
    const int h  = (i >> 3) & 7;
    const int l  = i >> 6;
    f32x4 acc = {0,0,0,0};
    float dn = 0.f;
    for (int sp = 0; sp < NSPLIT; ++sp) {
        const float* pr = num + (((size_t)(sp * H_ + h) * L_ + l) << 5) + d4;
        f32x4 t = *(const f32x4*)pr;
        acc[0] += t[0]; acc[1] += t[1]; acc[2] += t[2]; acc[3] += t[3];
        dn += den[(size_t)(sp * H_ + h) * L_ + l];
    }
    const float inv = 1.f / dn;
    f32x4 r = {acc[0]*inv, acc[1]*inv, acc[2]*inv, acc[3]*inv};
    *(f32x4*)(out + ((size_t)l * H_ + h) * D_ + d4) = r;
}

extern "C" void kernel_launch(void* const* d_in, const int* in_sizes, int n_in,
                              void* d_out, int out_size, void* d_ws, size_t ws_size,
                              hipStream_t stream) {
    const float* q = (const float*)d_in[0];
    const float* k = (const float*)d_in[1];
    const float* v = (const float*)d_in[2];
    float* out = (float*)d_out;
    const size_t nnum = (size_t)NSPLIT * H_ * L_ * 32;
    const size_t nden = (size_t)NSPLIT * H_ * L_;
    const size_t nkv  = (size_t)H_ * S_ * D_;              // bf16 elements per tensor
    const size_t need_v2 = (nnum + nden) * sizeof(float) + 2 * nkv * sizeof(__bf16);
    if (ws_size >= need_v2) {
        float* num = (float*)d_ws;
        float* den = num + nnum;
        __bf16* kbp = (__bf16*)(den + nden);
        __bf16* vtp = kbp + nkv;
        prep_k<<<dim3((H_ * S_ * D_ / 8) / 256), 256, 0, stream>>>(k, kbp);
        prep_v<<<dim3(S_ / 64, H_), 256, 0, stream>>>(v, vtp);
        fattn_v2<<<dim3(L_ / BM, H_, NSPLIT), 256, 0, stream>>>(
            kbp, vtp, q, num, den, S_ / NSPLIT);
        fattn_combine<<<dim3((L_ * H_ * D_ / 4) / 256), 256, 0, stream>>>(num, den, out);
    } else if (ws_size >= (nnum + nden) * sizeof(float)) {
        float* num = (float*)d_ws;
        float* den = num + nnum;
        fattn_main<false><<<dim3(L_ / BM, H_, NSPLIT), 256, 0, stream>>>(
            q, k, v, num, den, out, S_ / NSPLIT);
        fattn_combine<<<dim3((L_ * H_ * D_ / 4) / 256), 256, 0, stream>>>(num, den, out);
    } else {
        fattn_main<true><<<dim3(L_ / BM, H_, 1), 256, 0, stream>>>(
            q, k, v, nullptr, nullptr, out, S_);
    }
}

// Round 3
// 111.768 us; speedup vs baseline: 1.0069x; 1.0042x over previous
//
#include <hip/hip_runtime.h>
#include <hip/hip_bf16.h>

typedef __bf16 bf16x4 __attribute__((ext_vector_type(4)));
typedef __bf16 bf16x8 __attribute__((ext_vector_type(8)));
typedef float  f32x4  __attribute__((ext_vector_type(4)));

#define H_  8
#define D_  32
#define L_  4096
#define S_  4096
#define BM  64
#define BN  64
#define NSPLIT 4

static __device__ __forceinline__ f32x4 mfma_k16(bf16x4 a, bf16x4 b, f32x4 c) {
#if __has_builtin(__builtin_amdgcn_mfma_f32_16x16x16_bf16)
    return __builtin_amdgcn_mfma_f32_16x16x16_bf16(a, b, c, 0, 0, 0);
#elif __has_builtin(__builtin_amdgcn_mfma_f32_16x16x16bf16_1k)
    typedef short s16x4 __attribute__((ext_vector_type(4)));
    union U { bf16x4 h; s16x4 s; };
    U ua, ub; ua.h = a; ub.h = b;
    return __builtin_amdgcn_mfma_f32_16x16x16bf16_1k(ua.s, ub.s, c, 0, 0, 0);
#else
    asm("v_mfma_f32_16x16x16_bf16 %0, %1, %2, %0" : "+v"(c) : "v"(a), "v"(b));
    return c;
#endif
}

// ---------- pre-pass: K f32 [s][h][d] -> bf16 Kb [h][s][d] ----------
__global__ __launch_bounds__(256)
void prep_k(const float* __restrict__ kk, __bf16* __restrict__ kb)
{
    const int oi = blockIdx.x * 256 + threadIdx.x;   // one bf16x8 group
    const int h    = oi >> 14;                       // S_*D_/8 = 16384 groups/head
    const int s    = (oi >> 2) & (S_ - 1);
    const int dseg = (oi & 3) * 8;
    const float* ip = kk + (((size_t)s * H_ + h) * D_ + dseg);
    float4 a = *(const float4*)ip, b = *(const float4*)(ip + 4);
    bf16x8 o;
    o[0]=(__bf16)a.x; o[1]=(__bf16)a.y; o[2]=(__bf16)a.z; o[3]=(__bf16)a.w;
    o[4]=(__bf16)b.x; o[5]=(__bf16)b.y; o[6]=(__bf16)b.z; o[7]=(__bf16)b.w;
    *(bf16x8*)(kb + ((size_t)h * S_ + s) * D_ + dseg) = o;
}

// ---------- pre-pass: V f32 [s][h][d] -> bf16 Vtg [h][d][s] (transpose) ----------
__global__ __launch_bounds__(256)
void prep_v(const float* __restrict__ v, __bf16* __restrict__ vt)
{
    const int h  = blockIdx.y;
    const int s0 = blockIdx.x * 64;
    __shared__ __bf16 T[D_][72];
    const int sr = threadIdx.x >> 2, dseg = (threadIdx.x & 3) * 8;
    const float* ip = v + (((size_t)(s0 + sr) * H_ + h) * D_ + dseg);
    float4 a = *(const float4*)ip, b = *(const float4*)(ip + 4);
    float vv[8] = {a.x, a.y, a.z, a.w, b.x, b.y, b.z, b.w};
#pragma unroll
    for (int j = 0; j < 8; ++j) T[dseg + j][sr] = (__bf16)vv[j];
    __syncthreads();
    const int d = threadIdx.x >> 3, so = (threadIdx.x & 7) * 8;
    bf16x8 o = *(const bf16x8*)(&T[d][so]);
    *(bf16x8*)(vt + ((size_t)h * D_ + d) * S_ + s0 + so) = o;
}

// ---------- main kernel v3 ----------
// v2 staging (pre-converted bf16 K, pre-transposed bf16 V) PLUS:
//  * __launch_bounds__(256,8): v2's VGPR=36 is far under the 64-cap, so 8
//    blocks/CU now fit (LDS 8x19456=155.6KB<=160KB; 32 waves/CU = 100%
//    theoretical). Grid = 2048 = 256 CU x 8 -> ONE uniform pass, no tail.
//  * sb-pair ILP: both K fragments + all 4 V fragments of a pair loaded
//    before the MFMA/exp chain -> 2 QK MFMAs in flight, 8 exp2 batched,
//    breaks the per-sb serial ds_read->MFMA->exp->PV latency chain.
__global__ __launch_bounds__(256, 8)
void fattn_v2(const __bf16* __restrict__ kb, const __bf16* __restrict__ vtg,
              const float* __restrict__ q, float* __restrict__ num,
              float* __restrict__ den, int schunk)
{
    const int qt = blockIdx.x, h = blockIdx.y, sp = blockIdx.z;
    const int tid = threadIdx.x, wave = tid >> 6, lane = tid & 63;
    const int col = lane & 15, quad = lane >> 4;

    __shared__ __align__(16) __bf16 Ks[2][BN][40];
    __shared__ __align__(16) __bf16 Vt[2][D_][72];

    const float cs = 0.17677669529663687f * 1.4426950408889634f; // log2e/sqrt(32)

    const int qn = qt * BM + wave * 16 + col;
    bf16x8 qb;
    {
        const float* qp = q + ((size_t)qn * H_ + h) * D_ + quad * 8;
        float4 q0 = *(const float4*)qp;
        float4 q1 = *(const float4*)(qp + 4);
        qb[0]=(__bf16)(q0.x*cs); qb[1]=(__bf16)(q0.y*cs);
        qb[2]=(__bf16)(q0.z*cs); qb[3]=(__bf16)(q0.w*cs);
        qb[4]=(__bf16)(q1.x*cs); qb[5]=(__bf16)(q1.y*cs);
        qb[6]=(__bf16)(q1.z*cs); qb[7]=(__bf16)(q1.w*cs);
    }

    f32x4 o0 = {0,0,0,0}, o1 = {0,0,0,0}, accl = {0,0,0,0};
    const f32x4 zc = {0,0,0,0};
    const bf16x4 ones = {(__bf16)1.f, (__bf16)1.f, (__bf16)1.f, (__bf16)1.f};

    // staging indices
    const int srow = tid >> 2, kseg = (tid & 3) * 8;       // K: row, d-octave
    const int vd   = tid >> 3, vso  = (tid & 7) * 8;       // V: d-row, s-octave
    const int vcolw = (vso + 16 * (vd >> 3)) & 63;         // rotated write col base
    const int rot0  = (col >> 3) << 4;                     // read rotation for d=col

    const int sbeg = sp * schunk;
    const int T = schunk / BN;

    const __bf16* kptr = kb  + ((size_t)h * S_ + sbeg + srow) * D_ + kseg;
    const __bf16* vptr = vtg + ((size_t)h * D_ + vd) * S_ + sbeg + vso;

    bf16x8 kf = *(const bf16x8*)kptr;
    bf16x8 vf = *(const bf16x8*)vptr;
    bf16x8 kn = kf, vn = vf;

    for (int t = 0; t < T; ++t) {
        const int b = t & 1;
        // stage current regs -> LDS buffer b (b last read at t-2; barrier(t-1) protects)
        *(bf16x8*)(&Ks[b][srow][kseg]) = kf;
        *(bf16x8*)(&Vt[b][vd][vcolw])  = vf;
        if (t + 1 < T) {   // prefetch next tile; lands during this tile's compute
            kn = *(const bf16x8*)(kptr + (size_t)(t + 1) * BN * D_);
            vn = *(const bf16x8*)(vptr + (t + 1) * BN);
        }
        __syncthreads();   // single barrier per tile

#pragma unroll
        for (int sbp = 0; sbp < 2; ++sbp) {
            const int sb0 = sbp * 2, sb1 = sb0 + 1;
            // hoist ALL LDS reads of the pair ahead of the compute chain
            bf16x8 ka0 = *(const bf16x8*)(&Ks[b][sb0 * 16 + col][quad * 8]);
            bf16x8 ka1 = *(const bf16x8*)(&Ks[b][sb1 * 16 + col][quad * 8]);
            const int sc0 = sb0 * 16 + quad * 4;
            const int sc1 = sb1 * 16 + quad * 4;
            bf16x4 va00 = *(const bf16x4*)(&Vt[b][col     ][(sc0 + rot0)      & 63]);
            bf16x4 va01 = *(const bf16x4*)(&Vt[b][col + 16][(sc0 + rot0 + 32) & 63]);
            bf16x4 va10 = *(const bf16x4*)(&Vt[b][col     ][(sc1 + rot0)      & 63]);
            bf16x4 va11 = *(const bf16x4*)(&Vt[b][col + 16][(sc1 + rot0 + 32) & 63]);
            // two independent QK^T MFMAs in flight
            f32x4 st0 = __builtin_amdgcn_mfma_f32_16x16x32_bf16(ka0, qb, zc, 0, 0, 0);
            f32x4 st1 = __builtin_amdgcn_mfma_f32_16x16x32_bf16(ka1, qb, zc, 0, 0, 0);
            bf16x4 pb0, pb1;
#pragma unroll
            for (int r = 0; r < 4; ++r)
                pb0[r] = (__bf16)__builtin_amdgcn_exp2f(st0[r]);
#pragma unroll
            for (int r = 0; r < 4; ++r)
                pb1[r] = (__bf16)__builtin_amdgcn_exp2f(st1[r]);
            o0   = mfma_k16(va00, pb0, o0);
            o1   = mfma_k16(va01, pb0, o1);
            accl = mfma_k16(ones, pb0, accl);
            o0   = mfma_k16(va10, pb1, o0);
            o1   = mfma_k16(va11, pb1, o1);
            accl = mfma_k16(ones, pb1, accl);
        }
        kf = kn; vf = vn;
    }

    float* pr = num + (((size_t)(sp * H_ + h) * L_ + qn) << 5);
    *(f32x4*)(pr + quad * 4)      = o0;
    *(f32x4*)(pr + 16 + quad * 4) = o1;
    if (quad == 0) den[(size_t)(sp * H_ + h) * L_ + qn] = accl[0];
}

// ---------- v1 kernel kept verbatim as fallback (small-workspace paths) ----------
template<bool DIRECT>
__global__ __launch_bounds__(256, 6)
void fattn_main(const float* __restrict__ q, const float* __restrict__ kk,
                const float* __restrict__ v, float* __restrict__ num,
                float* __restrict__ den, float* __restrict__ out, int schunk)
{
    const int qt = blockIdx.x, h = blockIdx.y, sp = blockIdx.z;
    const int tid = threadIdx.x, wave = tid >> 6, lane = tid & 63;
    const int col = lane & 15, quad = lane >> 4;

    __shared__ __align__(16) __bf16 Ks[2][BN][40];
    __shared__ __align__(16) __bf16 Vt[2][D_][72];

    const float cs = 0.17677669529663687f * 1.4426950408889634f;

    const int qn = qt * BM + wave * 16 + col;
    bf16x8 qb;
    {
        const float* qp = q + ((size_t)qn * H_ + h) * D_ + quad * 8;
        float4 q0 = *(const float4*)qp;
        float4 q1 = *(const float4*)(qp + 4);
        qb[0]=(__bf16)(q0.x*cs); qb[1]=(__bf16)(q0.y*cs);
        qb[2]=(__bf16)(q0.z*cs); qb[3]=(__bf16)(q0.w*cs);
        qb[4]=(__bf16)(q1.x*cs); qb[5]=(__bf16)(q1.y*cs);
        qb[6]=(__bf16)(q1.z*cs); qb[7]=(__bf16)(q1.w*cs);
    }

    f32x4 o0 = {0,0,0,0}, o1 = {0,0,0,0}, accl = {0,0,0,0};
    const f32x4 zc = {0,0,0,0};
    const bf16x4 ones = {(__bf16)1.f, (__bf16)1.f, (__bf16)1.f, (__bf16)1.f};

    const int srow = tid >> 2;
    const int g    = tid & 3;
    const int dseg = g * 8;
    const int vcol = (srow + 16 * g) & 63;
    const int rot0 = (col >> 3) << 4;

    const int sbeg = sp * schunk;
    const int T = schunk / BN;

    float4 kf0, kf1, vf0, vf1;
    {
        const size_t goff = ((size_t)(sbeg + srow) * H_ + h) * D_ + dseg;
        kf0 = *(const float4*)(kk + goff);
        kf1 = *(const float4*)(kk + goff + 4);
        vf0 = *(const float4*)(v + goff);
        vf1 = *(const float4*)(v + goff + 4);
    }
    float4 kn0 = kf0, kn1 = kf1, vn0 = vf0, vn1 = vf1;

    for (int t = 0; t < T; ++t) {
        const int b = t & 1;
        {
            bf16x8 kb;
            kb[0]=(__bf16)kf0.x; kb[1]=(__bf16)kf0.y; kb[2]=(__bf16)kf0.z; kb[3]=(__bf16)kf0.w;
            kb[4]=(__bf16)kf1.x; kb[5]=(__bf16)kf1.y; kb[6]=(__bf16)kf1.z; kb[7]=(__bf16)kf1.w;
            *(bf16x8*)(&Ks[b][srow][dseg]) = kb;
            float vv[8] = {vf0.x, vf0.y, vf0.z, vf0.w, vf1.x, vf1.y, vf1.z, vf1.w};
#pragma unroll
            for (int j = 0; j < 8; ++j)
                Vt[b][dseg + j][vcol] = (__bf16)vv[j];
        }
        if (t + 1 < T) {
            const size_t goff = ((size_t)(sbeg + (t+1)*BN + srow) * H_ + h) * D_ + dseg;
            kn0 = *(const float4*)(kk + goff);
            kn1 = *(const float4*)(kk + goff + 4);
            vn0 = *(const float4*)(v + goff);
            vn1 = *(const float4*)(v + goff + 4);
        }
        __syncthreads();

#pragma unroll
        for (int sb = 0; sb < 4; ++sb) {
            bf16x8 ka = *(const bf16x8*)(&Ks[b][sb * 16 + col][quad * 8]);
            f32x4 st = __builtin_amdgcn_mfma_f32_16x16x32_bf16(ka, qb, zc, 0, 0, 0);
            bf16x4 pb;
#pragma unroll
            for (int r = 0; r < 4; ++r)
                pb[r] = (__bf16)__builtin_amdgcn_exp2f(st[r]);
            const int sc  = sb * 16 + quad * 4;
            bf16x4 va0 = *(const bf16x4*)(&Vt[b][col     ][(sc + rot0)      & 63]);
            bf16x4 va1 = *(const bf16x4*)(&Vt[b][col + 16][(sc + rot0 + 32) & 63]);
            o0   = mfma_k16(va0,  pb, o0);
            o1   = mfma_k16(va1,  pb, o1);
            accl = mfma_k16(ones, pb, accl);
        }
        kf0 = kn0; kf1 = kn1; vf0 = vn0; vf1 = vn1;
    }

    if (DIRECT) {
        const float inv = 1.f / accl[0];
        float* op = out + ((size_t)qn * H_ + h) * D_;
        f32x4 r0 = {o0[0]*inv, o0[1]*inv, o0[2]*inv, o0[3]*inv};
        f32x4 r1 = {o1[0]*inv, o1[1]*inv, o1[2]*inv, o1[3]*inv};
        *(f32x4*)(op + quad * 4)      = r0;
        *(f32x4*)(op + 16 + quad * 4) = r1;
    } else {
        float* pr = num + (((size_t)(sp * H_ + h) * L_ + qn) << 5);
        *(f32x4*)(pr + quad * 4)      = o0;
        *(f32x4*)(pr + 16 + quad * 4) = o1;
        if (quad == 0) den[(size_t)(sp * H_ + h) * L_ + qn] = accl[0];
    }
}

__global__ __launch_bounds__(256)
void fattn_combine(const float* __restrict__ num, const float* __restrict__ den,
                   float* __restrict__ out)
{
    const int i  = blockIdx.x * 256 + threadIdx.x;
    const int d4 = (i & 7) * 4;
    const int h  = (i >> 3) & 7;
    const int l  = i >> 6;
    f32x4 acc = {0,0,0,0};
    float dn = 0.f;
    for (int sp = 0; sp < NSPLIT; ++sp) {
        const float* pr = num + (((size_t)(sp * H_ + h) * L_ + l) << 5) + d4;
        f32x4 t = *(const f32x4*)pr;
        acc[0] += t[0]; acc[1] += t[1]; acc[2] += t[2]; acc[3] += t[3];
        dn += den[(size_t)(sp * H_ + h) * L_ + l];
    }
    const float inv = 1.f / dn;
    f32x4 r = {acc[0]*inv, acc[1]*inv, acc[2]*inv, acc[3]*inv};
    *(f32x4*)(out + ((size_t)l * H_ + h) * D_ + d4) = r;
}

extern "C" void kernel_launch(void* const* d_in, const int* in_sizes, int n_in,
                              void* d_out, int out_size, void* d_ws, size_t ws_size,
                              hipStream_t stream) {
    const float* q = (const float*)d_in[0];
    const float* k = (const float*)d_in[1];
    const float* v = (const float*)d_in[2];
    float* out = (float*)d_out;
    const size_t nnum = (size_t)NSPLIT * H_ * L_ * 32;
    const size_t nden = (size_t)NSPLIT * H_ * L_;
    const size_t nkv  = (size_t)H_ * S_ * D_;              // bf16 elements per tensor
    const size_t need_v2 = (nnum + nden) * sizeof(float) + 2 * nkv * sizeof(__bf16);
    if (ws_size >= need_v2) {
        float* num = (float*)d_ws;
        float* den = num + nnum;
        __bf16* kbp = (__bf16*)(den + nden);
        __bf16* vtp = kbp + nkv;
        prep_k<<<dim3((H_ * S_ * D_ / 8) / 256), 256, 0, stream>>>(k, kbp);
        prep_v<<<dim3(S_ / 64, H_), 256, 0, stream>>>(v, vtp);
        fattn_v2<<<dim3(L_ / BM, H_, NSPLIT), 256, 0, stream>>>(
            kbp, vtp, q, num, den, S_ / NSPLIT);
        fattn_combine<<<dim3((L_ * H_ * D_ / 4) / 256), 256, 0, stream>>>(num, den, out);
    } else if (ws_size >= (nnum + nden) * sizeof(float)) {
        float* num = (float*)d_ws;
        float* den = num + nnum;
        fattn_main<false><<<dim3(L_ / BM, H_, NSPLIT), 256, 0, stream>>>(
            q, k, v, num, den, out, S_ / NSPLIT);
        fattn_combine<<<dim3((L_ * H_ * D_ / 4) / 256), 256, 0, stream>>>(num, den, out);
    } else {
        fattn_main<true><<<dim3(L_ / BM, H_, 1), 256, 0, stream>>>(
            q, k, v, nullptr, nullptr, out, S_);
    }
}

// Round 5
// 105.439 us; speedup vs baseline: 1.0673x; 1.0600x over previous
//
#include <hip/hip_runtime.h>
#include <hip/hip_bf16.h>

typedef __bf16 bf16x4 __attribute__((ext_vector_type(4)));
typedef __bf16 bf16x8 __attribute__((ext_vector_type(8)));
typedef float  f32x4  __attribute__((ext_vector_type(4)));
typedef float  f32x16 __attribute__((ext_vector_type(16)));

#define H_  8
#define D_  32
#define L_  4096
#define S_  4096
#define BM  64
#define BM4 128
#define BN  64
#define NSPLIT 4

static __device__ __forceinline__ f32x4 mfma_k16(bf16x4 a, bf16x4 b, f32x4 c) {
#if __has_builtin(__builtin_amdgcn_mfma_f32_16x16x16_bf16)
    return __builtin_amdgcn_mfma_f32_16x16x16_bf16(a, b, c, 0, 0, 0);
#else
    asm("v_mfma_f32_16x16x16_bf16 %0, %1, %2, %0" : "+v"(c) : "v"(a), "v"(b));
    return c;
#endif
}

// ---------- pre-pass: K f32 [s][h][d] -> bf16 Kb [h][s][d] ----------
__global__ __launch_bounds__(256)
void prep_k(const float* __restrict__ kk, __bf16* __restrict__ kb)
{
    const int oi = blockIdx.x * 256 + threadIdx.x;
    const int h    = oi >> 14;
    const int s    = (oi >> 2) & (S_ - 1);
    const int dseg = (oi & 3) * 8;
    const float* ip = kk + (((size_t)s * H_ + h) * D_ + dseg);
    float4 a = *(const float4*)ip, b = *(const float4*)(ip + 4);
    bf16x8 o;
    o[0]=(__bf16)a.x; o[1]=(__bf16)a.y; o[2]=(__bf16)a.z; o[3]=(__bf16)a.w;
    o[4]=(__bf16)b.x; o[5]=(__bf16)b.y; o[6]=(__bf16)b.z; o[7]=(__bf16)b.w;
    *(bf16x8*)(kb + ((size_t)h * S_ + s) * D_ + dseg) = o;
}

// ---------- pre-pass: V f32 [s][h][d] -> bf16 Vtg [h][d][s] (transpose) ----------
__global__ __launch_bounds__(256)
void prep_v(const float* __restrict__ v, __bf16* __restrict__ vt)
{
    const int h  = blockIdx.y;
    const int s0 = blockIdx.x * 64;
    __shared__ __bf16 T[D_][72];
    const int sr = threadIdx.x >> 2, dseg = (threadIdx.x & 3) * 8;
    const float* ip = v + (((size_t)(s0 + sr) * H_ + h) * D_ + dseg);
    float4 a = *(const float4*)ip, b = *(const float4*)(ip + 4);
    float vv[8] = {a.x, a.y, a.z, a.w, b.x, b.y, b.z, b.w};
#pragma unroll
    for (int j = 0; j < 8; ++j) T[dseg + j][sr] = (__bf16)vv[j];
    __syncthreads();
    const int d = threadIdx.x >> 3, so = (threadIdx.x & 7) * 8;
    bf16x8 o = *(const bf16x8*)(&T[d][so]);
    *(bf16x8*)(vt + ((size_t)h * D_ + d) * S_ + s0 + so) = o;
}

// ---------- main kernel v4: 32x32x16 MFMA formulation ----------
// Per wave: 32 q-rows x 64 s per tile (BM4=128, 4 waves/block, 1024 blocks
// = exactly 4 blocks/CU). S^T form: st = K*Q (m=s, n=q). P regs at
// row s=(reg&3)+8*(reg>>2)+4*(lane>>5) are rearranged to the PV B-operand
// (k=8*(lane>>5)+j) with 8 cvt_pk + 4 permlane32_swap per tile-half (T12).
// Denominator: f32 partial sums (VALU) + one shfl_xor(32) at the end --
// keeps the extra ones-MFMA off the matrix pipe.
__global__ __launch_bounds__(256, 4)
void fattn_v4(const __bf16* __restrict__ kb, const __bf16* __restrict__ vtg,
              const float* __restrict__ q, float* __restrict__ num,
              float* __restrict__ den, int schunk)
{
    const int qt = blockIdx.x, h = blockIdx.y, sp = blockIdx.z;
    const int tid = threadIdx.x, wq = tid >> 6, lane = tid & 63;
    const int ln = lane & 31, hl = lane >> 5;

    __shared__ __align__(16) __bf16 Ks[2][64][40];   // 80B rows: conflict-free b128
    __shared__ __align__(16) __bf16 Vt[2][D_][72];   // 144B rows: conflict-free b128

    const float cs = 0.17677669529663687f * 1.4426950408889634f; // log2e/sqrt(32)

    const int qn = qt * BM4 + wq * 32 + ln;
    bf16x8 qf0, qf1;   // B-operand: n=q(ln), k(d) = 16*kh + 8*hl + j
    {
        const float* qp = q + ((size_t)qn * H_ + h) * D_ + hl * 8;
        float4 a = *(const float4*)qp,        b = *(const float4*)(qp + 4);
        float4 c = *(const float4*)(qp + 16), d = *(const float4*)(qp + 20);
        qf0[0]=(__bf16)(a.x*cs); qf0[1]=(__bf16)(a.y*cs);
        qf0[2]=(__bf16)(a.z*cs); qf0[3]=(__bf16)(a.w*cs);
        qf0[4]=(__bf16)(b.x*cs); qf0[5]=(__bf16)(b.y*cs);
        qf0[6]=(__bf16)(b.z*cs); qf0[7]=(__bf16)(b.w*cs);
        qf1[0]=(__bf16)(c.x*cs); qf1[1]=(__bf16)(c.y*cs);
        qf1[2]=(__bf16)(c.z*cs); qf1[3]=(__bf16)(c.w*cs);
        qf1[4]=(__bf16)(d.x*cs); qf1[5]=(__bf16)(d.y*cs);
        qf1[6]=(__bf16)(d.z*cs); qf1[7]=(__bf16)(d.w*cs);
    }

    f32x16 o = {0,0,0,0,0,0,0,0,0,0,0,0,0,0,0,0};
    const f32x16 z16 = {0,0,0,0,0,0,0,0,0,0,0,0,0,0,0,0};
    f32x4 accl = {0,0,0,0};

    // staging indices (256 threads cover 64x32 K-tile and 32x64 Vt-tile)
    const int srow = tid >> 2, kseg = (tid & 3) * 8;
    const int vd   = tid >> 3, vso  = (tid & 7) * 8;

    const int sbeg = sp * schunk;
    const int T = schunk / BN;

    const __bf16* kptr = kb  + ((size_t)h * S_ + sbeg + srow) * D_ + kseg;
    const __bf16* vptr = vtg + ((size_t)h * D_ + vd) * S_ + sbeg + vso;

    bf16x8 kf = *(const bf16x8*)kptr;
    bf16x8 vf = *(const bf16x8*)vptr;
    bf16x8 kn = kf, vn = vf;

    for (int t = 0; t < T; ++t) {
        const int b = t & 1;
        // stage current regs -> LDS buffer b (b last read at t-2; barrier(t-1) protects)
        *(bf16x8*)(&Ks[b][srow][kseg]) = kf;
        *(bf16x8*)(&Vt[b][vd][vso])    = vf;
        if (t + 1 < T) {   // prefetch next tile; lands during this tile's compute
            kn = *(const bf16x8*)(kptr + (size_t)(t + 1) * BN * D_);
            vn = *(const bf16x8*)(vptr + (t + 1) * BN);
        }
        __syncthreads();   // single barrier per tile

#pragma unroll
        for (int sh = 0; sh < 2; ++sh) {
            // A-operand K frags: m=s (32 rows), k(d) = 16*kh + 8*hl + j
            bf16x8 ka0 = *(const bf16x8*)(&Ks[b][sh * 32 + ln][hl * 8]);
            bf16x8 ka1 = *(const bf16x8*)(&Ks[b][sh * 32 + ln][16 + hl * 8]);
            f32x16 st = __builtin_amdgcn_mfma_f32_32x32x16_bf16(ka0, qf0, z16, 0, 0, 0);
            st = __builtin_amdgcn_mfma_f32_32x32x16_bf16(ka1, qf1, st, 0, 0, 0);
            float p[16];
#pragma unroll
            for (int r = 0; r < 16; ++r) p[r] = __builtin_amdgcn_exp2f(st[r]);
            // denominator partials (4 independent chains)
            accl[0] += p[0]  + p[1]  + p[2]  + p[3];
            accl[1] += p[4]  + p[5]  + p[6]  + p[7];
            accl[2] += p[8]  + p[9]  + p[10] + p[11];
            accl[3] += p[12] + p[13] + p[14] + p[15];
            // rearrange P rows -> PV B-operand frags (two 16-s slots per half)
#pragma unroll
            for (int u = 0; u < 2; ++u) {
                unsigned A, B, C, D;
                asm("v_cvt_pk_bf16_f32 %0, %1, %2" : "=v"(A) : "v"(p[u*8+0]), "v"(p[u*8+1]));
                asm("v_cvt_pk_bf16_f32 %0, %1, %2" : "=v"(B) : "v"(p[u*8+2]), "v"(p[u*8+3]));
                asm("v_cvt_pk_bf16_f32 %0, %1, %2" : "=v"(C) : "v"(p[u*8+4]), "v"(p[u*8+5]));
                asm("v_cvt_pk_bf16_f32 %0, %1, %2" : "=v"(D) : "v"(p[u*8+6]), "v"(p[u*8+7]));
                // swap hi-half of first with lo-half of second:
                // A' = {A.lo|C.lo} -> j0-1,  C' = {A.hi|C.hi} -> j4-5 (and B/D for j2-3,j6-7)
                asm("v_permlane32_swap_b32 %0, %1" : "+v"(A), "+v"(C));
                asm("v_permlane32_swap_b32 %0, %1" : "+v"(B), "+v"(D));
                union { unsigned w[4]; bf16x8 f; } pb;
                pb.w[0] = A; pb.w[1] = B; pb.w[2] = C; pb.w[3] = D;
                const int slot = sh * 2 + u;
                // A-operand V frag: m=d (32 rows), k(s) = 16*slot + 8*hl + j
                bf16x8 va = *(const bf16x8*)(&Vt[b][ln][slot * 16 + hl * 8]);
                o = __builtin_amdgcn_mfma_f32_32x32x16_bf16(va, pb.f, o, 0, 0, 0);
            }
        }
        kf = kn; vf = vn;
    }

    float dsum = accl[0] + accl[1] + accl[2] + accl[3];
    dsum += __shfl_xor(dsum, 32, 64);   // combine the two s-half partials per q

    // O regs: n=q=ln, m=d=(reg&3)+8*(reg>>2)+4*hl -> four f32x4 chunks
    float* pr = num + (((size_t)(sp * H_ + h) * L_ + qn) << 5);
    f32x4 w0 = {o[0],  o[1],  o[2],  o[3]};
    f32x4 w1 = {o[4],  o[5],  o[6],  o[7]};
    f32x4 w2 = {o[8],  o[9],  o[10], o[11]};
    f32x4 w3 = {o[12], o[13], o[14], o[15]};
    *(f32x4*)(pr      + hl * 4) = w0;
    *(f32x4*)(pr + 8  + hl * 4) = w1;
    *(f32x4*)(pr + 16 + hl * 4) = w2;
    *(f32x4*)(pr + 24 + hl * 4) = w3;
    if (hl == 0) den[(size_t)(sp * H_ + h) * L_ + qn] = dsum;
}

// ---------- v1 kernel kept verbatim as fallback (small-workspace paths) ----------
template<bool DIRECT>
__global__ __launch_bounds__(256, 6)
void fattn_main(const float* __restrict__ q, const float* __restrict__ kk,
                const float* __restrict__ v, float* __restrict__ num,
                float* __restrict__ den, float* __restrict__ out, int schunk)
{
    const int qt = blockIdx.x, h = blockIdx.y, sp = blockIdx.z;
    const int tid = threadIdx.x, wave = tid >> 6, lane = tid & 63;
    const int col = lane & 15, quad = lane >> 4;

    __shared__ __align__(16) __bf16 Ks[2][BN][40];
    __shared__ __align__(16) __bf16 Vt[2][D_][72];

    const float cs = 0.17677669529663687f * 1.4426950408889634f;

    const int qn = qt * BM + wave * 16 + col;
    bf16x8 qb;
    {
        const float* qp = q + ((size_t)qn * H_ + h) * D_ + quad * 8;
        float4 q0 = *(const float4*)qp;
        float4 q1 = *(const float4*)(qp + 4);
        qb[0]=(__bf16)(q0.x*cs); qb[1]=(__bf16)(q0.y*cs);
        qb[2]=(__bf16)(q0.z*cs); qb[3]=(__bf16)(q0.w*cs);
        qb[4]=(__bf16)(q1.x*cs); qb[5]=(__bf16)(q1.y*cs);
        qb[6]=(__bf16)(q1.z*cs); qb[7]=(__bf16)(q1.w*cs);
    }

    f32x4 o0 = {0,0,0,0}, o1 = {0,0,0,0}, accl = {0,0,0,0};
    const f32x4 zc = {0,0,0,0};
    const bf16x4 ones = {(__bf16)1.f, (__bf16)1.f, (__bf16)1.f, (__bf16)1.f};

    const int srow = tid >> 2;
    const int g    = tid & 3;
    const int dseg = g * 8;
    const int vcol = (srow + 16 * g) & 63;
    const int rot0 = (col >> 3) << 4;

    const int sbeg = sp * schunk;
    const int T = schunk / BN;

    float4 kf0, kf1, vf0, vf1;
    {
        const size_t goff = ((size_t)(sbeg + srow) * H_ + h) * D_ + dseg;
        kf0 = *(const float4*)(kk + goff);
        kf1 = *(const float4*)(kk + goff + 4);
        vf0 = *(const float4*)(v + goff);
        vf1 = *(const float4*)(v + goff + 4);
    }
    float4 kn0 = kf0, kn1 = kf1, vn0 = vf0, vn1 = vf1;

    for (int t = 0; t < T; ++t) {
        const int b = t & 1;
        {
            bf16x8 kb;
            kb[0]=(__bf16)kf0.x; kb[1]=(__bf16)kf0.y; kb[2]=(__bf16)kf0.z; kb[3]=(__bf16)kf0.w;
            kb[4]=(__bf16)kf1.x; kb[5]=(__bf16)kf1.y; kb[6]=(__bf16)kf1.z; kb[7]=(__bf16)kf1.w;
            *(bf16x8*)(&Ks[b][srow][dseg]) = kb;
            float vv[8] = {vf0.x, vf0.y, vf0.z, vf0.w, vf1.x, vf1.y, vf1.z, vf1.w};
#pragma unroll
            for (int j = 0; j < 8; ++j)
                Vt[b][dseg + j][vcol] = (__bf16)vv[j];
        }
        if (t + 1 < T) {
            const size_t goff = ((size_t)(sbeg + (t+1)*BN + srow) * H_ + h) * D_ + dseg;
            kn0 = *(const float4*)(kk + goff);
            kn1 = *(const float4*)(kk + goff + 4);
            vn0 = *(const float4*)(v + goff);
            vn1 = *(const float4*)(v + goff + 4);
        }
        __syncthreads();

#pragma unroll
        for (int sb = 0; sb < 4; ++sb) {
            bf16x8 ka = *(const bf16x8*)(&Ks[b][sb * 16 + col][quad * 8]);
            f32x4 st = __builtin_amdgcn_mfma_f32_16x16x32_bf16(ka, qb, zc, 0, 0, 0);
            bf16x4 pb;
#pragma unroll
            for (int r = 0; r < 4; ++r)
                pb[r] = (__bf16)__builtin_amdgcn_exp2f(st[r]);
            const int sc  = sb * 16 + quad * 4;
            bf16x4 va0 = *(const bf16x4*)(&Vt[b][col     ][(sc + rot0)      & 63]);
            bf16x4 va1 = *(const bf16x4*)(&Vt[b][col + 16][(sc + rot0 + 32) & 63]);
            o0   = mfma_k16(va0,  pb, o0);
            o1   = mfma_k16(va1,  pb, o1);
            accl = mfma_k16(ones, pb, accl);
        }
        kf0 = kn0; kf1 = kn1; vf0 = vn0; vf1 = vn1;
    }

    if (DIRECT) {
        const float inv = 1.f / accl[0];
        float* op = out + ((size_t)qn * H_ + h) * D_;
        f32x4 r0 = {o0[0]*inv, o0[1]*inv, o0[2]*inv, o0[3]*inv};
        f32x4 r1 = {o1[0]*inv, o1[1]*inv, o1[2]*inv, o1[3]*inv};
        *(f32x4*)(op + quad * 4)      = r0;
        *(f32x4*)(op + 16 + quad * 4) = r1;
    } else {
        float* pr = num + (((size_t)(sp * H_ + h) * L_ + qn) << 5);
        *(f32x4*)(pr + quad * 4)      = o0;
        *(f32x4*)(pr + 16 + quad * 4) = o1;
        if (quad == 0) den[(size_t)(sp * H_ + h) * L_ + qn] = accl[0];
    }
}

__global__ __launch_bounds__(256)
void fattn_combine(const float* __restrict__ num, const float* __restrict__ den,
                   float* __restrict__ out)
{
    const int i  = blockIdx.x * 256 + threadIdx.x;
    const int d4 = (i & 7) * 4;
    const int h  = (i >> 3) & 7;
    const int l  = i >> 6;
    f32x4 acc = {0,0,0,0};
    float dn = 0.f;
    for (int sp = 0; sp < NSPLIT; ++sp) {
        const float* pr = num + (((size_t)(sp * H_ + h) * L_ + l) << 5) + d4;
        f32x4 t = *(const f32x4*)pr;
        acc[0] += t[0]; acc[1] += t[1]; acc[2] += t[2]; acc[3] += t[3];
        dn += den[(size_t)(sp * H_ + h) * L_ + l];
    }
    const float inv = 1.f / dn;
    f32x4 r = {acc[0]*inv, acc[1]*inv, acc[2]*inv, acc[3]*inv};
    *(f32x4*)(out + ((size_t)l * H_ + h) * D_ + d4) = r;
}

extern "C" void kernel_launch(void* const* d_in, const int* in_sizes, int n_in,
                              void* d_out, int out_size, void* d_ws, size_t ws_size,
                              hipStream_t stream) {
    const float* q = (const float*)d_in[0];
    const float* k = (const float*)d_in[1];
    const float* v = (const float*)d_in[2];
    float* out = (float*)d_out;
    const size_t nnum = (size_t)NSPLIT * H_ * L_ * 32;
    const size_t nden = (size_t)NSPLIT * H_ * L_;
    const size_t nkv  = (size_t)H_ * S_ * D_;              // bf16 elements per tensor
    const size_t need_v4 = (nnum + nden) * sizeof(float) + 2 * nkv * sizeof(__bf16);
    if (ws_size >= need_v4) {
        float* num = (float*)d_ws;
        float* den = num + nnum;
        __bf16* kbp = (__bf16*)(den + nden);
        __bf16* vtp = kbp + nkv;
        prep_k<<<dim3((H_ * S_ * D_ / 8) / 256), 256, 0, stream>>>(k, kbp);
        prep_v<<<dim3(S_ / 64, H_), 256, 0, stream>>>(v, vtp);
        fattn_v4<<<dim3(L_ / BM4, H_, NSPLIT), 256, 0, stream>>>(
            kbp, vtp, q, num, den, S_ / NSPLIT);
        fattn_combine<<<dim3((L_ * H_ * D_ / 4) / 256), 256, 0, stream>>>(num, den, out);
    } else if (ws_size >= (nnum + nden) * sizeof(float)) {
        float* num = (float*)d_ws;
        float* den = num + nnum;
        fattn_main<false><<<dim3(L_ / BM, H_, NSPLIT), 256, 0, stream>>>(
            q, k, v, num, den, out, S_ / NSPLIT);
        fattn_combine<<<dim3((L_ * H_ * D_ / 4) / 256), 256, 0, stream>>>(num, den, out);
    } else {
        fattn_main<true><<<dim3(L_ / BM, H_, 1), 256, 0, stream>>>(
            q, k, v, nullptr, nullptr, out, S_);
    }
}

// Round 6
// 104.195 us; speedup vs baseline: 1.0801x; 1.0119x over previous
//
#include <hip/hip_runtime.h>
#include <hip/hip_bf16.h>

typedef __bf16 bf16x4 __attribute__((ext_vector_type(4)));
typedef __bf16 bf16x8 __attribute__((ext_vector_type(8)));
typedef float  f32x4  __attribute__((ext_vector_type(4)));
typedef float  f32x16 __attribute__((ext_vector_type(16)));

#define H_  8
#define D_  32
#define L_  4096
#define S_  4096
#define BM  64
#define BM4 128
#define BN  64
#define NSPLIT 4

static __device__ __forceinline__ f32x4 mfma_k16(bf16x4 a, bf16x4 b, f32x4 c) {
#if __has_builtin(__builtin_amdgcn_mfma_f32_16x16x16_bf16)
    return __builtin_amdgcn_mfma_f32_16x16x16_bf16(a, b, c, 0, 0, 0);
#else
    asm("v_mfma_f32_16x16x16_bf16 %0, %1, %2, %0" : "+v"(c) : "v"(a), "v"(b));
    return c;
#endif
}

// ---------- merged pre-pass: K convert + V transpose (one launch) ----------
__global__ __launch_bounds__(256)
void prep_kv(const float* __restrict__ kk, const float* __restrict__ v,
             __bf16* __restrict__ kb, __bf16* __restrict__ vt)
{
    const int h  = blockIdx.y;
    const int s0 = blockIdx.x * 64;
    const int sr = threadIdx.x >> 2, dseg = (threadIdx.x & 3) * 8;
    // K: straight convert [s][h][d] -> [h][s][d]
    {
        const float* ip = kk + (((size_t)(s0 + sr) * H_ + h) * D_ + dseg);
        float4 a = *(const float4*)ip, b = *(const float4*)(ip + 4);
        bf16x8 o;
        o[0]=(__bf16)a.x; o[1]=(__bf16)a.y; o[2]=(__bf16)a.z; o[3]=(__bf16)a.w;
        o[4]=(__bf16)b.x; o[5]=(__bf16)b.y; o[6]=(__bf16)b.z; o[7]=(__bf16)b.w;
        *(bf16x8*)(kb + ((size_t)h * S_ + s0 + sr) * D_ + dseg) = o;
    }
    // V: transpose [s][h][d] -> [h][d][s] via LDS
    __shared__ __bf16 T[D_][72];
    {
        const float* ip = v + (((size_t)(s0 + sr) * H_ + h) * D_ + dseg);
        float4 a = *(const float4*)ip, b = *(const float4*)(ip + 4);
        float vv[8] = {a.x, a.y, a.z, a.w, b.x, b.y, b.z, b.w};
#pragma unroll
        for (int j = 0; j < 8; ++j) T[dseg + j][sr] = (__bf16)vv[j];
    }
    __syncthreads();
    const int d = threadIdx.x >> 3, so = (threadIdx.x & 7) * 8;
    bf16x8 o = *(const bf16x8*)(&T[d][so]);
    *(bf16x8*)(vt + ((size_t)h * D_ + d) * S_ + s0 + so) = o;
}

// ---------- main kernel v5: 32x32x16, waves = 2 q-groups x 2 s-halves ----------
// v4 read the full 64s K/V tile in EVERY wave (8 b128/wave-tile) -> LDS-BW
// bound (~13us of ~34). v5: each wave covers 64q x 32s; K frags (2 b128) and
// V frags (2 b128, hoisted, reused across both q-subblocks) halve block-tile
// LDS reads (32 -> 16 b128). O/den are s-partial; one end-of-kernel LDS
// reduction (ws=1 -> ws=0) combines the halves.
__global__ __launch_bounds__(256, 4)
void fattn_v5(const __bf16* __restrict__ kb, const __bf16* __restrict__ vtg,
              const float* __restrict__ q, float* __restrict__ num,
              float* __restrict__ den, int schunk)
{
    const int qt = blockIdx.x, h = blockIdx.y, sp = blockIdx.z;
    const int tid = threadIdx.x, wave = tid >> 6, lane = tid & 63;
    const int ln = lane & 31, hl = lane >> 5;
    const int wq = wave >> 1, ws = wave & 1;

    __shared__ __align__(16) __bf16 Ks[2][64][40];   // 80B rows: conflict-free b128
    __shared__ __align__(16) __bf16 Vt[2][D_][72];   // 144B rows: conflict-free b128

    const float cs = 0.17677669529663687f * 1.4426950408889634f; // log2e/sqrt(32)

    // Q fragments for the wave's two 32-q subblocks
    bf16x8 qf[2][2];
#pragma unroll
    for (int qh = 0; qh < 2; ++qh) {
        const int qn = qt * BM4 + wq * 64 + qh * 32 + ln;
        const float* qp = q + ((size_t)qn * H_ + h) * D_ + hl * 8;
        float4 a = *(const float4*)qp,        b2 = *(const float4*)(qp + 4);
        float4 c = *(const float4*)(qp + 16), d2 = *(const float4*)(qp + 20);
        qf[qh][0][0]=(__bf16)(a.x*cs);  qf[qh][0][1]=(__bf16)(a.y*cs);
        qf[qh][0][2]=(__bf16)(a.z*cs);  qf[qh][0][3]=(__bf16)(a.w*cs);
        qf[qh][0][4]=(__bf16)(b2.x*cs); qf[qh][0][5]=(__bf16)(b2.y*cs);
        qf[qh][0][6]=(__bf16)(b2.z*cs); qf[qh][0][7]=(__bf16)(b2.w*cs);
        qf[qh][1][0]=(__bf16)(c.x*cs);  qf[qh][1][1]=(__bf16)(c.y*cs);
        qf[qh][1][2]=(__bf16)(c.z*cs);  qf[qh][1][3]=(__bf16)(c.w*cs);
        qf[qh][1][4]=(__bf16)(d2.x*cs); qf[qh][1][5]=(__bf16)(d2.y*cs);
        qf[qh][1][6]=(__bf16)(d2.z*cs); qf[qh][1][7]=(__bf16)(d2.w*cs);
    }

    f32x16 o[2];
    o[0] = (f32x16){0,0,0,0,0,0,0,0,0,0,0,0,0,0,0,0};
    o[1] = (f32x16){0,0,0,0,0,0,0,0,0,0,0,0,0,0,0,0};
    const f32x16 z16 = {0,0,0,0,0,0,0,0,0,0,0,0,0,0,0,0};
    f32x4 accl[2];
    accl[0] = (f32x4){0,0,0,0};
    accl[1] = (f32x4){0,0,0,0};

    // staging indices (256 threads cover 64x32 K-tile and 32x64 Vt-tile)
    const int srow = tid >> 2, kseg = (tid & 3) * 8;
    const int vd   = tid >> 3, vso  = (tid & 7) * 8;

    const int sbeg = sp * schunk;
    const int T = schunk / BN;

    const __bf16* kptr = kb  + ((size_t)h * S_ + sbeg + srow) * D_ + kseg;
    const __bf16* vptr = vtg + ((size_t)h * D_ + vd) * S_ + sbeg + vso;

    bf16x8 kf = *(const bf16x8*)kptr;
    bf16x8 vf = *(const bf16x8*)vptr;
    bf16x8 kn = kf, vn = vf;

    for (int t = 0; t < T; ++t) {
        const int b = t & 1;
        *(bf16x8*)(&Ks[b][srow][kseg]) = kf;
        *(bf16x8*)(&Vt[b][vd][vso])    = vf;
        if (t + 1 < T) {
            kn = *(const bf16x8*)(kptr + (size_t)(t + 1) * BN * D_);
            vn = *(const bf16x8*)(vptr + (t + 1) * BN);
        }
        __syncthreads();   // single barrier per tile

        // wave's K frags (its 32-s half), shared across both q-subblocks
        bf16x8 ka0 = *(const bf16x8*)(&Ks[b][ws * 32 + ln][hl * 8]);
        bf16x8 ka1 = *(const bf16x8*)(&Ks[b][ws * 32 + ln][16 + hl * 8]);
        // wave's V frags (its 32-s half), hoisted: no qh dependence
        bf16x8 va0 = *(const bf16x8*)(&Vt[b][ln][ws * 32 + hl * 8]);
        bf16x8 va1 = *(const bf16x8*)(&Vt[b][ln][ws * 32 + 16 + hl * 8]);

#pragma unroll
        for (int qh = 0; qh < 2; ++qh) {
            f32x16 st = __builtin_amdgcn_mfma_f32_32x32x16_bf16(ka0, qf[qh][0], z16, 0, 0, 0);
            st = __builtin_amdgcn_mfma_f32_32x32x16_bf16(ka1, qf[qh][1], st, 0, 0, 0);
            float p[16];
#pragma unroll
            for (int r = 0; r < 16; ++r) p[r] = __builtin_amdgcn_exp2f(st[r]);
            accl[qh][0] += p[0]  + p[1]  + p[2]  + p[3];
            accl[qh][1] += p[4]  + p[5]  + p[6]  + p[7];
            accl[qh][2] += p[8]  + p[9]  + p[10] + p[11];
            accl[qh][3] += p[12] + p[13] + p[14] + p[15];
#pragma unroll
            for (int u = 0; u < 2; ++u) {
                unsigned A, B, C, D;
                asm("v_cvt_pk_bf16_f32 %0, %1, %2" : "=v"(A) : "v"(p[u*8+0]), "v"(p[u*8+1]));
                asm("v_cvt_pk_bf16_f32 %0, %1, %2" : "=v"(B) : "v"(p[u*8+2]), "v"(p[u*8+3]));
                asm("v_cvt_pk_bf16_f32 %0, %1, %2" : "=v"(C) : "v"(p[u*8+4]), "v"(p[u*8+5]));
                asm("v_cvt_pk_bf16_f32 %0, %1, %2" : "=v"(D) : "v"(p[u*8+6]), "v"(p[u*8+7]));
                asm("v_permlane32_swap_b32 %0, %1" : "+v"(A), "+v"(C));
                asm("v_permlane32_swap_b32 %0, %1" : "+v"(B), "+v"(D));
                union { unsigned w[4]; bf16x8 f; } pb;
                pb.w[0] = A; pb.w[1] = B; pb.w[2] = C; pb.w[3] = D;
                o[qh] = __builtin_amdgcn_mfma_f32_32x32x16_bf16(u ? va1 : va0, pb.f, o[qh], 0, 0, 0);
            }
        }
        kf = kn; vf = vn;
    }

    // combine per-wave denominator partials (within s-half)
    float dsum[2];
#pragma unroll
    for (int qh = 0; qh < 2; ++qh) {
        float s4 = accl[qh][0] + accl[qh][1] + accl[qh][2] + accl[qh][3];
        s4 += __shfl_xor(s4, 32, 64);
        dsum[qh] = s4;
    }

    // s-half reduction: ws=1 waves dump O/den into (now-dead) LDS buffers;
    // ws=0 waves add and write out. wq=0 -> Ks region, wq=1 -> Vt region.
    __syncthreads();
    float* rb = (wq == 0) ? (float*)&Ks[0][0][0] : (float*)&Vt[0][0][0];
    if (ws == 1) {
#pragma unroll
        for (int qh = 0; qh < 2; ++qh) {
#pragma unroll
            for (int r = 0; r < 16; ++r)
                rb[(qh * 16 + r) * 64 + lane] = o[qh][r];
            rb[2048 + qh * 64 + lane] = dsum[qh];
        }
    }
    __syncthreads();
    if (ws == 0) {
#pragma unroll
        for (int qh = 0; qh < 2; ++qh) {
#pragma unroll
            for (int r = 0; r < 16; ++r)
                o[qh][r] += rb[(qh * 16 + r) * 64 + lane];
            dsum[qh] += rb[2048 + qh * 64 + lane];
            const int qn = qt * BM4 + wq * 64 + qh * 32 + ln;
            float* pr = num + (((size_t)(sp * H_ + h) * L_ + qn) << 5);
            f32x4 w0 = {o[qh][0],  o[qh][1],  o[qh][2],  o[qh][3]};
            f32x4 w1 = {o[qh][4],  o[qh][5],  o[qh][6],  o[qh][7]};
            f32x4 w2 = {o[qh][8],  o[qh][9],  o[qh][10], o[qh][11]};
            f32x4 w3 = {o[qh][12], o[qh][13], o[qh][14], o[qh][15]};
            *(f32x4*)(pr      + hl * 4) = w0;
            *(f32x4*)(pr + 8  + hl * 4) = w1;
            *(f32x4*)(pr + 16 + hl * 4) = w2;
            *(f32x4*)(pr + 24 + hl * 4) = w3;
            if (hl == 0) den[(size_t)(sp * H_ + h) * L_ + qn] = dsum[qh];
        }
    }
}

// ---------- v1 kernel kept verbatim as fallback (small-workspace paths) ----------
template<bool DIRECT>
__global__ __launch_bounds__(256, 6)
void fattn_main(const float* __restrict__ q, const float* __restrict__ kk,
                const float* __restrict__ v, float* __restrict__ num,
                float* __restrict__ den, float* __restrict__ out, int schunk)
{
    const int qt = blockIdx.x, h = blockIdx.y, sp = blockIdx.z;
    const int tid = threadIdx.x, wave = tid >> 6, lane = tid & 63;
    const int col = lane & 15, quad = lane >> 4;

    __shared__ __align__(16) __bf16 Ks[2][BN][40];
    __shared__ __align__(16) __bf16 Vt[2][D_][72];

    const float cs = 0.17677669529663687f * 1.4426950408889634f;

    const int qn = qt * BM + wave * 16 + col;
    bf16x8 qb;
    {
        const float* qp = q + ((size_t)qn * H_ + h) * D_ + quad * 8;
        float4 q0 = *(const float4*)qp;
        float4 q1 = *(const float4*)(qp + 4);
        qb[0]=(__bf16)(q0.x*cs); qb[1]=(__bf16)(q0.y*cs);
        qb[2]=(__bf16)(q0.z*cs); qb[3]=(__bf16)(q0.w*cs);
        qb[4]=(__bf16)(q1.x*cs); qb[5]=(__bf16)(q1.y*cs);
        qb[6]=(__bf16)(q1.z*cs); qb[7]=(__bf16)(q1.w*cs);
    }

    f32x4 o0 = {0,0,0,0}, o1 = {0,0,0,0}, accl = {0,0,0,0};
    const f32x4 zc = {0,0,0,0};
    const bf16x4 ones = {(__bf16)1.f, (__bf16)1.f, (__bf16)1.f, (__bf16)1.f};

    const int srow = tid >> 2;
    const int g    = tid & 3;
    const int dseg = g * 8;
    const int vcol = (srow + 16 * g) & 63;
    const int rot0 = (col >> 3) << 4;

    const int sbeg = sp * schunk;
    const int T = schunk / BN;

    float4 kf0, kf1, vf0, vf1;
    {
        const size_t goff = ((size_t)(sbeg + srow) * H_ + h) * D_ + dseg;
        kf0 = *(const float4*)(kk + goff);
        kf1 = *(const float4*)(kk + goff + 4);
        vf0 = *(const float4*)(v + goff);
        vf1 = *(const float4*)(v + goff + 4);
    }
    float4 kn0 = kf0, kn1 = kf1, vn0 = vf0, vn1 = vf1;

    for (int t = 0; t < T; ++t) {
        const int b = t & 1;
        {
            bf16x8 kb;
            kb[0]=(__bf16)kf0.x; kb[1]=(__bf16)kf0.y; kb[2]=(__bf16)kf0.z; kb[3]=(__bf16)kf0.w;
            kb[4]=(__bf16)kf1.x; kb[5]=(__bf16)kf1.y; kb[6]=(__bf16)kf1.z; kb[7]=(__bf16)kf1.w;
            *(bf16x8*)(&Ks[b][srow][dseg]) = kb;
            float vv[8] = {vf0.x, vf0.y, vf0.z, vf0.w, vf1.x, vf1.y, vf1.z, vf1.w};
#pragma unroll
            for (int j = 0; j < 8; ++j)
                Vt[b][dseg + j][vcol] = (__bf16)vv[j];
        }
        if (t + 1 < T) {
            const size_t goff = ((size_t)(sbeg + (t+1)*BN + srow) * H_ + h) * D_ + dseg;
            kn0 = *(const float4*)(kk + goff);
            kn1 = *(const float4*)(kk + goff + 4);
            vn0 = *(const float4*)(v + goff);
            vn1 = *(const float4*)(v + goff + 4);
        }
        __syncthreads();

#pragma unroll
        for (int sb = 0; sb < 4; ++sb) {
            bf16x8 ka = *(const bf16x8*)(&Ks[b][sb * 16 + col][quad * 8]);
            f32x4 st = __builtin_amdgcn_mfma_f32_16x16x32_bf16(ka, qb, zc, 0, 0, 0);
            bf16x4 pb;
#pragma unroll
            for (int r = 0; r < 4; ++r)
                pb[r] = (__bf16)__builtin_amdgcn_exp2f(st[r]);
            const int sc  = sb * 16 + quad * 4;
            bf16x4 va0 = *(const bf16x4*)(&Vt[b][col     ][(sc + rot0)      & 63]);
            bf16x4 va1 = *(const bf16x4*)(&Vt[b][col + 16][(sc + rot0 + 32) & 63]);
            o0   = mfma_k16(va0,  pb, o0);
            o1   = mfma_k16(va1,  pb, o1);
            accl = mfma_k16(ones, pb, accl);
        }
        kf0 = kn0; kf1 = kn1; vf0 = vn0; vf1 = vn1;
    }

    if (DIRECT) {
        const float inv = 1.f / accl[0];
        float* op = out + ((size_t)qn * H_ + h) * D_;
        f32x4 r0 = {o0[0]*inv, o0[1]*inv, o0[2]*inv, o0[3]*inv};
        f32x4 r1 = {o1[0]*inv, o1[1]*inv, o1[2]*inv, o1[3]*inv};
        *(f32x4*)(op + quad * 4)      = r0;
        *(f32x4*)(op + 16 + quad * 4) = r1;
    } else {
        float* pr = num + (((size_t)(sp * H_ + h) * L_ + qn) << 5);
        *(f32x4*)(pr + quad * 4)      = o0;
        *(f32x4*)(pr + 16 + quad * 4) = o1;
        if (quad == 0) den[(size_t)(sp * H_ + h) * L_ + qn] = accl[0];
    }
}

__global__ __launch_bounds__(256)
void fattn_combine(const float* __restrict__ num, const float* __restrict__ den,
                   float* __restrict__ out)
{
    const int i  = blockIdx.x * 256 + threadIdx.x;
    const int d4 = (i & 7) * 4;
    const int h  = (i >> 3) & 7;
    const int l  = i >> 6;
    f32x4 acc = {0,0,0,0};
    float dn = 0.f;
    for (int sp = 0; sp < NSPLIT; ++sp) {
        const float* pr = num + (((size_t)(sp * H_ + h) * L_ + l) << 5) + d4;
        f32x4 t = *(const f32x4*)pr;
        acc[0] += t[0]; acc[1] += t[1]; acc[2] += t[2]; acc[3] += t[3];
        dn += den[(size_t)(sp * H_ + h) * L_ + l];
    }
    const float inv = 1.f / dn;
    f32x4 r = {acc[0]*inv, acc[1]*inv, acc[2]*inv, acc[3]*inv};
    *(f32x4*)(out + ((size_t)l * H_ + h) * D_ + d4) = r;
}

extern "C" void kernel_launch(void* const* d_in, const int* in_sizes, int n_in,
                              void* d_out, int out_size, void* d_ws, size_t ws_size,
                              hipStream_t stream) {
    const float* q = (const float*)d_in[0];
    const float* k = (const float*)d_in[1];
    const float* v = (const float*)d_in[2];
    float* out = (float*)d_out;
    const size_t nnum = (size_t)NSPLIT * H_ * L_ * 32;
    const size_t nden = (size_t)NSPLIT * H_ * L_;
    const size_t nkv  = (size_t)H_ * S_ * D_;              // bf16 elements per tensor
    const size_t need_v5 = (nnum + nden) * sizeof(float) + 2 * nkv * sizeof(__bf16);
    if (ws_size >= need_v5) {
        float* num = (float*)d_ws;
        float* den = num + nnum;
        __bf16* kbp = (__bf16*)(den + nden);
        __bf16* vtp = kbp + nkv;
        prep_kv<<<dim3(S_ / 64, H_), 256, 0, stream>>>(k, v, kbp, vtp);
        fattn_v5<<<dim3(L_ / BM4, H_, NSPLIT), 256, 0, stream>>>(
            kbp, vtp, q, num, den, S_ / NSPLIT);
        fattn_combine<<<dim3((L_ * H_ * D_ / 4) / 256), 256, 0, stream>>>(num, den, out);
    } else if (ws_size >= (nnum + nden) * sizeof(float)) {
        float* num = (float*)d_ws;
        float* den = num + nnum;
        fattn_main<false><<<dim3(L_ / BM, H_, NSPLIT), 256, 0, stream>>>(
            q, k, v, num, den, out, S_ / NSPLIT);
        fattn_combine<<<dim3((L_ * H_ * D_ / 4) / 256), 256, 0, stream>>>(num, den, out);
    } else {
        fattn_main<true><<<dim3(L_ / BM, H_, 1), 256, 0, stream>>>(
            q, k, v, nullptr, nullptr, out, S_);
    }
}